// Round 1
// baseline (1140.206 us; speedup 1.0000x reference)
//
#include <hip/hip_runtime.h>
#include <hip/hip_bf16.h>
#include <math.h>

// Problem constants (from reference)
#define T_TOK 65536
#define D_DIM 2048
#define E_EXP 128
#define K_TOP 4
#define G_GRP 2
#define GS    64   // experts per group

// GEMM tile config
#define BM 64
#define BN 128
#define BK 16
// LDS pads: +4 floats keeps per-k fragments 16B-aligned and breaks write conflicts
#define PA (BM + 4)
#define PB (BN + 4)

// logits[t][e] = dot(x[t,:], W[e,:]) + bias[e]
// f32 products, f64 accumulation of BK-tile partials => ~1e-7 logit error
// (jax-grade; needed so top-k selection matches the numpy reference exactly).
__global__ __launch_bounds__(256) void gemm_logits(
    const float* __restrict__ x, const float* __restrict__ W,
    const float* __restrict__ bias, float* __restrict__ logits) {
  __shared__ float As[BK][PA];  // [kk][row]
  __shared__ float Bs[BK][PB];  // [kk][expert]

  const int tid = threadIdx.x;
  const int t0  = blockIdx.x * BM;
  const int c   = tid & 15;   // expert group of 8: experts c*8 .. c*8+7
  const int r   = tid >> 4;   // token group of 4: tokens r*4 .. r*4+3

  double acc[4][8];
#pragma unroll
  for (int i = 0; i < 4; ++i)
#pragma unroll
    for (int j = 0; j < 8; ++j) acc[i][j] = 0.0;

  for (int k0 = 0; k0 < D_DIM; k0 += BK) {
    // stage A: 64 rows x 16 k (consecutive tid -> consecutive k: 64B segments)
#pragma unroll
    for (int i = 0; i < 4; ++i) {
      int lin = i * 256 + tid;
      int kk = lin & 15, row = lin >> 4;
      As[kk][row] = x[(size_t)(t0 + row) * D_DIM + k0 + kk];
    }
    // stage B: 128 experts x 16 k
#pragma unroll
    for (int i = 0; i < 8; ++i) {
      int lin = i * 256 + tid;
      int kk = lin & 15, e = lin >> 4;
      Bs[kk][e] = W[(size_t)e * D_DIM + k0 + kk];
    }
    __syncthreads();

    float part[4][8];
#pragma unroll
    for (int i = 0; i < 4; ++i)
#pragma unroll
      for (int j = 0; j < 8; ++j) part[i][j] = 0.0f;

#pragma unroll
    for (int kk = 0; kk < BK; ++kk) {
      float a[4], b[8];
#pragma unroll
      for (int i = 0; i < 4; ++i) a[i] = As[kk][r * 4 + i];
#pragma unroll
      for (int j = 0; j < 8; ++j) b[j] = Bs[kk][c * 8 + j];
#pragma unroll
      for (int i = 0; i < 4; ++i)
#pragma unroll
        for (int j = 0; j < 8; ++j) part[i][j] = fmaf(a[i], b[j], part[i][j]);
    }
#pragma unroll
    for (int i = 0; i < 4; ++i)
#pragma unroll
      for (int j = 0; j < 8; ++j) acc[i][j] += (double)part[i][j];
    __syncthreads();
  }

#pragma unroll
  for (int i = 0; i < 4; ++i) {
    size_t rowoff = (size_t)(t0 + r * 4 + i) * E_EXP;
#pragma unroll
    for (int j = 0; j < 8; ++j) {
      int e = c * 8 + j;
      logits[rowoff + e] = (float)(acc[i][j] + (double)bias[e]);
    }
  }
}

// One thread per token: group-limited top-4 selection + normalized weights.
// Softmax denominator cancels: w_i = exp(l_i-M)/sum_sel exp(l_j-M).
__global__ __launch_bounds__(256) void gate_topk(
    const float* __restrict__ logits, float* __restrict__ w_out,
    float* __restrict__ idx_out) {
  const int t = blockIdx.x * 256 + threadIdx.x;
  const float* row = logits + (size_t)t * E_EXP;

  // pass A: per-group top-2 logits (ordering by logits == by scores)
  float m1[G_GRP], m2[G_GRP];
#pragma unroll
  for (int g = 0; g < G_GRP; ++g) {
    m1[g] = -INFINITY;
    m2[g] = -INFINITY;
    for (int e = 0; e < GS; ++e) {
      float v = row[g * GS + e];
      if (v > m1[g]) { m2[g] = m1[g]; m1[g] = v; }
      else if (v > m2[g]) { m2[g] = v; }
    }
  }
  float M = fmaxf(m1[0], m1[1]);
  // group rep = sum of top-2 scores; common denominator cancels
  float r0 = expf(m1[0] - M) + expf(m2[0] - M);
  float r1 = expf(m1[1] - M) + expf(m2[1] - M);
  int g = (r1 > r0) ? 1 : 0;  // tie -> lower group index (top_k semantics)

  // pass B: top-4 within chosen group, strict '>' => ties keep lower index
  float v4[4] = {-INFINITY, -INFINITY, -INFINITY, -INFINITY};
  int i4[4] = {0, 0, 0, 0};
  const int base = g * GS;
  for (int e = 0; e < GS; ++e) {
    float v = row[base + e];
    if (v > v4[3]) {
      if (v > v4[1]) {
        if (v > v4[0]) {
          v4[3] = v4[2]; i4[3] = i4[2];
          v4[2] = v4[1]; i4[2] = i4[1];
          v4[1] = v4[0]; i4[1] = i4[0];
          v4[0] = v; i4[0] = e;
        } else {
          v4[3] = v4[2]; i4[3] = i4[2];
          v4[2] = v4[1]; i4[2] = i4[1];
          v4[1] = v; i4[1] = e;
        }
      } else {
        if (v > v4[2]) {
          v4[3] = v4[2]; i4[3] = i4[2];
          v4[2] = v; i4[2] = e;
        } else {
          v4[3] = v; i4[3] = e;
        }
      }
    }
  }

  float s[4], sum = 0.0f;
#pragma unroll
  for (int j = 0; j < 4; ++j) { s[j] = expf(v4[j] - M); sum += s[j]; }
  float denom = fmaxf(sum, 1e-9f);
#pragma unroll
  for (int j = 0; j < 4; ++j) {
    w_out[(size_t)t * K_TOP + j] = s[j] / denom;
    idx_out[(size_t)t * K_TOP + j] = (float)(base + i4[j]);
  }
}

extern "C" void kernel_launch(void* const* d_in, const int* in_sizes, int n_in,
                              void* d_out, int out_size, void* d_ws, size_t ws_size,
                              hipStream_t stream) {
  (void)in_sizes; (void)n_in; (void)out_size; (void)ws_size;
  const float* x    = (const float*)d_in[0];
  const float* W    = (const float*)d_in[1];
  const float* bias = (const float*)d_in[2];
  float* out    = (float*)d_out;
  float* logits = (float*)d_ws;  // 65536*128*4 = 32 MB scratch

  gemm_logits<<<T_TOK / BM, 256, 0, stream>>>(x, W, bias, logits);
  gate_topk<<<T_TOK / 256, 256, 0, stream>>>(logits, out, out + (size_t)T_TOK * K_TOP);
}

// Round 2
// 1048.285 us; speedup vs baseline: 1.0877x; 1.0877x over previous
//
#include <hip/hip_runtime.h>
#include <math.h>

// Problem constants
#define T_TOK 65536
#define D_DIM 2048
#define E_EXP 128
#define K_TOP 4
#define GS    64   // experts per group (G=2)

// GEMM tile config
#define BM 64
#define BN 128
#define BK 16
#define NT (D_DIM / BK)   // 128 k-tiles
// A tile LDS row stride: 68 floats = 272B = 17*16B (16B-aligned rows, 2-way-max
// bank aliasing on both the staged writes and the b128 fragment reads -> free)
#define PA 68
// B tile LDS row stride with swizzled 8-float block layout pos(b)=8b+4*(b/4):
// the 16 lanes' b128 fragment reads then cover every bank exactly 2x (free)
// instead of the 4-way conflict of the naive contiguous layout.
#define PBROW 140
// logits tile row stride (528B = 33*16B aligned for float4 stores)
#define LROW 132

__device__ __forceinline__ int bpos(int b) { return 8 * b + 4 * (b >> 2); }

// Fused: logits = x@W.T + bias (f32 products, f64 tile-drain accumulation,
// ~1e-7 logit error so top-k matches the f64 numpy reference), then
// group-limited top-4 gating from the LDS logits tile.
__global__ __launch_bounds__(256) void gemm_gate(
    const float* __restrict__ x, const float* __restrict__ W,
    const float* __restrict__ bias, float* __restrict__ w_out,
    float* __restrict__ idx_out) {
  // union region: K-loop uses front 3328 floats as A/B tiles; epilogue reuses
  // the whole buffer as the 64x132 logits tile.
  __shared__ float smem[BM * LROW];  // 33792 B
  float* As = smem;                  // [BK][PA]
  float* Bs = smem + BK * PA;        // [BK][PBROW]

  const int tid = threadIdx.x;
  const int t0  = blockIdx.x * BM;
  const int c   = tid & 15;   // expert block: experts c*8..c*8+7
  const int r   = tid >> 4;   // token block: tokens r*4..r*4+3

  // staging decomposition: one float4 (4 consecutive k) per row per thread
  const int kqa  = tid & 3;   // k-quad 0..3  (BK=16)
  const int rowa = tid >> 2;  // 0..63 (token row for A, expert row e0 for B)

  const float* xa  = x + (size_t)(t0 + rowa) * D_DIM + kqa * 4;
  const float* wb0 = W + (size_t)rowa * D_DIM + kqa * 4;
  const float* wb1 = W + (size_t)(rowa + 64) * D_DIM + kqa * 4;

  // LDS write offsets for the staged float4 (scalar writes, row-strided)
  const int wA  = (kqa * 4) * PA + rowa;
  const int pe0 = bpos(rowa >> 3) + (rowa & 7);
  const int pe1 = pe0 + 72;  // bpos(b+8) = bpos(b) + 72
  const int wB  = (kqa * 4) * PBROW;

  const int bposc = bpos(c);

  // prefetch tile 0
  float4 av  = *(const float4*)(xa);
  float4 bv0 = *(const float4*)(wb0);
  float4 bv1 = *(const float4*)(wb1);

  double acc[4][8];
#pragma unroll
  for (int i = 0; i < 4; ++i)
#pragma unroll
    for (int j = 0; j < 8; ++j) acc[i][j] = 0.0;

  for (int t = 0; t < NT; ++t) {
    __syncthreads();  // previous tile's compute done before overwrite
    As[wA]          = av.x;
    As[wA + PA]     = av.y;
    As[wA + 2 * PA] = av.z;
    As[wA + 3 * PA] = av.w;
    Bs[wB + pe0]             = bv0.x;
    Bs[wB + pe0 + PBROW]     = bv0.y;
    Bs[wB + pe0 + 2 * PBROW] = bv0.z;
    Bs[wB + pe0 + 3 * PBROW] = bv0.w;
    Bs[wB + pe1]             = bv1.x;
    Bs[wB + pe1 + PBROW]     = bv1.y;
    Bs[wB + pe1 + 2 * PBROW] = bv1.z;
    Bs[wB + pe1 + 3 * PBROW] = bv1.w;
    __syncthreads();

    // register prefetch of tile t+1 overlaps compute of tile t
    if (t + 1 < NT) {
      const int off = (t + 1) * BK;
      av  = *(const float4*)(xa + off);
      bv0 = *(const float4*)(wb0 + off);
      bv1 = *(const float4*)(wb1 + off);
    }

    float part[4][8];
#pragma unroll
    for (int i = 0; i < 4; ++i)
#pragma unroll
      for (int j = 0; j < 8; ++j) part[i][j] = 0.0f;

#pragma unroll
    for (int kk = 0; kk < BK; ++kk) {
      float4 a  = *(const float4*)(As + kk * PA + r * 4);
      float4 b0 = *(const float4*)(Bs + kk * PBROW + bposc);
      float4 b1 = *(const float4*)(Bs + kk * PBROW + bposc + 4);
      float af[4] = {a.x, a.y, a.z, a.w};
      float bf[8] = {b0.x, b0.y, b0.z, b0.w, b1.x, b1.y, b1.z, b1.w};
#pragma unroll
      for (int i = 0; i < 4; ++i)
#pragma unroll
        for (int j = 0; j < 8; ++j) part[i][j] = fmaf(af[i], bf[j], part[i][j]);
    }
#pragma unroll
    for (int i = 0; i < 4; ++i)
#pragma unroll
      for (int j = 0; j < 8; ++j) acc[i][j] += (double)part[i][j];
  }

  __syncthreads();  // all compute done; smem becomes the logits tile

  // epilogue 1: logits tile -> LDS (bias added in f64, one f32 rounding)
#pragma unroll
  for (int i = 0; i < 4; ++i) {
    float* Lr = smem + (r * 4 + i) * LROW + c * 8;
    float4 v0, v1;
    v0.x = (float)(acc[i][0] + (double)bias[c * 8 + 0]);
    v0.y = (float)(acc[i][1] + (double)bias[c * 8 + 1]);
    v0.z = (float)(acc[i][2] + (double)bias[c * 8 + 2]);
    v0.w = (float)(acc[i][3] + (double)bias[c * 8 + 3]);
    v1.x = (float)(acc[i][4] + (double)bias[c * 8 + 4]);
    v1.y = (float)(acc[i][5] + (double)bias[c * 8 + 5]);
    v1.z = (float)(acc[i][6] + (double)bias[c * 8 + 6]);
    v1.w = (float)(acc[i][7] + (double)bias[c * 8 + 7]);
    *(float4*)Lr = v0;
    *(float4*)(Lr + 4) = v1;
  }
  __syncthreads();

  // epilogue 2: one thread per token, group-limited top-4 selection.
  // Softmax denominator cancels: w_i = exp(l_i-M)/sum_sel exp(l_j-M).
  if (tid < BM) {
    const float* row = smem + tid * LROW;

    float m1[2], m2[2];
#pragma unroll
    for (int g = 0; g < 2; ++g) {
      m1[g] = -INFINITY;
      m2[g] = -INFINITY;
      for (int e = 0; e < GS; ++e) {
        float v = row[g * GS + e];
        if (v > m1[g]) { m2[g] = m1[g]; m1[g] = v; }
        else if (v > m2[g]) { m2[g] = v; }
      }
    }
    float M = fmaxf(m1[0], m1[1]);
    float r0 = expf(m1[0] - M) + expf(m2[0] - M);
    float r1 = expf(m1[1] - M) + expf(m2[1] - M);
    int g = (r1 > r0) ? 1 : 0;  // tie -> lower group index

    float v4[4] = {-INFINITY, -INFINITY, -INFINITY, -INFINITY};
    int i4[4] = {0, 0, 0, 0};
    const int base = g * GS;
    for (int e = 0; e < GS; ++e) {
      float v = row[base + e];
      if (v > v4[3]) {
        if (v > v4[1]) {
          if (v > v4[0]) {
            v4[3] = v4[2]; i4[3] = i4[2];
            v4[2] = v4[1]; i4[2] = i4[1];
            v4[1] = v4[0]; i4[1] = i4[0];
            v4[0] = v; i4[0] = e;
          } else {
            v4[3] = v4[2]; i4[3] = i4[2];
            v4[2] = v4[1]; i4[2] = i4[1];
            v4[1] = v; i4[1] = e;
          }
        } else {
          if (v > v4[2]) {
            v4[3] = v4[2]; i4[3] = i4[2];
            v4[2] = v; i4[2] = e;
          } else {
            v4[3] = v; i4[3] = e;
          }
        }
      }
    }

    float s[4], sum = 0.0f;
#pragma unroll
    for (int j = 0; j < 4; ++j) { s[j] = expf(v4[j] - M); sum += s[j]; }
    float denom = fmaxf(sum, 1e-9f);
    const int t = t0 + tid;
#pragma unroll
    for (int j = 0; j < 4; ++j) {
      w_out[(size_t)t * K_TOP + j] = s[j] / denom;
      idx_out[(size_t)t * K_TOP + j] = (float)(base + i4[j]);
    }
  }
}

extern "C" void kernel_launch(void* const* d_in, const int* in_sizes, int n_in,
                              void* d_out, int out_size, void* d_ws, size_t ws_size,
                              hipStream_t stream) {
  (void)in_sizes; (void)n_in; (void)out_size; (void)d_ws; (void)ws_size;
  const float* x    = (const float*)d_in[0];
  const float* W    = (const float*)d_in[1];
  const float* bias = (const float*)d_in[2];
  float* out = (float*)d_out;

  gemm_gate<<<T_TOK / BM, 256, 0, stream>>>(x, W, bias, out,
                                            out + (size_t)T_TOK * K_TOP);
}